// Round 16
// baseline (93.065 us; speedup 1.0000x reference)
//
#include <hip/hip_runtime.h>
#include <hip/hip_bf16.h>

#define NGROUP 256   // B * (SEQ/TG)
#define NSLOT  128   // experts * sets
#define TG     32    // tokens per group
#define DM     1024  // model dim
#define FF     32    // expert size

#define LSCALE     4096.0f
#define INV_LSCALE (1.0f / 4096.0f)

typedef unsigned int  uint;
typedef unsigned short ushort;
typedef unsigned char uchar;
typedef __attribute__((ext_vector_type(4))) float f32x4;
typedef __attribute__((ext_vector_type(8))) short bf16x8;
typedef __attribute__((ext_vector_type(8))) _Float16 f16x8;

__device__ __forceinline__ ushort f2bf(float f) {
    uint u = __float_as_uint(f);
    u += 0x7FFFu + ((u >> 16) & 1u);   // RNE
    return (ushort)(u >> 16);
}
__device__ __forceinline__ uint pk2(float a, float b) {
    return (uint)f2bf(a) | ((uint)f2bf(b) << 16);
}

// async global->LDS, 16B per lane; dst wave-uniform base (+lane*16 implicit)
__device__ __forceinline__ void gload_lds16(const void* g, void* l) {
    __builtin_amdgcn_global_load_lds(
        (const __attribute__((address_space(1))) uint*)g,
        (__attribute__((address_space(3))) uint*)l, 16, 0, 0);
}

// ---------------------------------------------------------------------------
// K1 mega-kernel (v9-proven, UNCHANGED): one launch, three block families.
//  blocks 0..511    : logits + tie-broken argmax + fused x->bf16 cast (+idx8)
//  blocks 512..767  : f1 -> f1F bf16 (MFMA-B fragment order)
//  blocks 768..1279 : f2 -> f2T[es][d][f] bf16
// ---------------------------------------------------------------------------
__global__ __launch_bounds__(256) void k_fused1(
    const float* __restrict__ x, const float* __restrict__ ctrl,
    const float* __restrict__ f1, const float* __restrict__ f2,
    int* __restrict__ idx, uchar* __restrict__ idx8, ushort* __restrict__ xb,
    ushort* __restrict__ f1F, ushort* __restrict__ f2T)
{
    __shared__ float smem[4 * 32 * 64];   // 32 KB
    const int t = threadIdx.x;

    if (blockIdx.x < 512) {
        float* Lp = smem;
        const int g  = blockIdx.x >> 1;
        const int nh = blockIdx.x & 1;
        const int w = t >> 6;
        const int lane = t & 63;
        const int lrow = lane & 15;
        const int lk8 = (lane >> 4) * 8;

        const size_t xoff0 = ((size_t)g * TG + lrow) * DM + w * 256 + lk8;
        const float* xr0 = x + xoff0;
        const float* xr1 = xr0 + 16 * DM;

        f32x4 ahh[2][4], ax[2][4];
#pragma unroll
        for (int mt = 0; mt < 2; ++mt)
#pragma unroll
            for (int nt = 0; nt < 4; ++nt) {
                ahh[mt][nt] = (f32x4){0.f, 0.f, 0.f, 0.f};
                ax[mt][nt]  = (f32x4){0.f, 0.f, 0.f, 0.f};
            }

        for (int ks = 0; ks < 8; ++ks) {
            f16x8 Ah[2], Al[2];
#pragma unroll
            for (int mt = 0; mt < 2; ++mt) {
                const float* p = (mt ? xr1 : xr0) + ks * 32;
                float xe[8];
                *(float4*)&xe[0] = *(const float4*)p;
                *(float4*)&xe[4] = *(const float4*)(p + 4);
                union { f16x8 v; _Float16 e[8]; } H, L;
#pragma unroll
                for (int j = 0; j < 8; ++j) {
                    const _Float16 h = (_Float16)xe[j];
                    H.e[j] = h;
                    L.e[j] = (_Float16)((xe[j] - (float)h) * LSCALE);
                }
                Ah[mt] = H.v; Al[mt] = L.v;
                if (nh == 0) {
                    uint4 o;
                    o.x = pk2(xe[0], xe[1]); o.y = pk2(xe[2], xe[3]);
                    o.z = pk2(xe[4], xe[5]); o.w = pk2(xe[6], xe[7]);
                    *(uint4*)(xb + xoff0 + (size_t)mt * 16 * DM + ks * 32) = o;
                }
            }
            const int kslice = w * 8 + ks;
#pragma unroll
            for (int nt = 0; nt < 4; ++nt) {
                const float* cp = ctrl
                    + (size_t)(kslice * 32 + ((lane >> 4) << 3)) * NSLOT
                    + nh * 64 + nt * 16 + (lane & 15);
                union { f16x8 v; _Float16 e[8]; } BH, BL;
#pragma unroll
                for (int j = 0; j < 8; ++j) {
                    const float c = cp[(size_t)j * NSLOT];
                    const _Float16 h = (_Float16)c;
                    BH.e[j] = h;
                    BL.e[j] = (_Float16)((c - (float)h) * LSCALE);
                }
#pragma unroll
                for (int mt = 0; mt < 2; ++mt) {
                    ahh[mt][nt] = __builtin_amdgcn_mfma_f32_16x16x32_f16(Ah[mt], BH.v, ahh[mt][nt], 0, 0, 0);
                    ax[mt][nt]  = __builtin_amdgcn_mfma_f32_16x16x32_f16(Al[mt], BH.v, ax[mt][nt], 0, 0, 0);
                    ax[mt][nt]  = __builtin_amdgcn_mfma_f32_16x16x32_f16(Ah[mt], BL.v, ax[mt][nt], 0, 0, 0);
                }
            }
        }

#pragma unroll
        for (int mt = 0; mt < 2; ++mt)
#pragma unroll
            for (int nt = 0; nt < 4; ++nt)
#pragma unroll
                for (int r = 0; r < 4; ++r) {
                    const int trow = mt * 16 + (lane >> 4) * 4 + r;
                    const int nl = nt * 16 + lrow;
                    Lp[(w * TG + trow) * 64 + nl] =
                        ahh[mt][nt][r] + ax[mt][nt][r] * INV_LSCALE;
                }
        __syncthreads();

        for (int i = t * 4; i < TG * 64; i += 256 * 4) {
            f32x4 s0 = *(const f32x4*)&Lp[i];
            f32x4 s1 = *(const f32x4*)&Lp[2048 + i];
            f32x4 s2 = *(const f32x4*)&Lp[4096 + i];
            f32x4 s3 = *(const f32x4*)&Lp[6144 + i];
            *(f32x4*)&Lp[i] = (s0 + s1) + (s2 + s3);
        }
        __syncthreads();

        if (t < 64) {
            const int n = t;
            float best = -1e30f;
            int bi = 0;
#pragma unroll
            for (int tt = 0; tt < TG; ++tt) {
                const float v = Lp[tt * 64 + n] + (float)tt * (1e-6f / 31.0f);
                if (v >= best) { best = v; bi = tt; }   // later token wins ties
            }
            idx[g * NSLOT + nh * 64 + n] = bi;
            idx8[g * NSLOT + nh * 64 + n] = (uchar)bi;
        }
    } else if (blockIdx.x < 768) {
        float* Ltr = smem;   // [64][33]
        const int i1 = blockIdx.x - 512;
        const int es = i1 >> 1;
        const int dh = i1 & 1;
        for (int d0 = dh * 512; d0 < dh * 512 + 512; d0 += 64) {
            const int dd = t >> 2, f0 = (t & 3) * 8;
            const float* src = f1 + (size_t)(d0 + dd) * 4096 + es * FF + f0;
            float4 a = *(const float4*)src;
            float4 b = *(const float4*)(src + 4);
            __syncthreads();
            float* Lq = &Ltr[dd * 33 + f0];
            Lq[0] = a.x; Lq[1] = a.y; Lq[2] = a.z; Lq[3] = a.w;
            Lq[4] = b.x; Lq[5] = b.y; Lq[6] = b.z; Lq[7] = b.w;
            __syncthreads();
            const int f = t & 31, koct = t >> 5;
            const int nt = f >> 4;
            const int kg = d0 + koct * 8;
            const int kslice = kg >> 5;
            const int lane2 = (f & 15) | (((kg >> 3) & 3) << 4);
            uint4 o;
            o.x = pk2(Ltr[(koct * 8 + 0) * 33 + f], Ltr[(koct * 8 + 1) * 33 + f]);
            o.y = pk2(Ltr[(koct * 8 + 2) * 33 + f], Ltr[(koct * 8 + 3) * 33 + f]);
            o.z = pk2(Ltr[(koct * 8 + 4) * 33 + f], Ltr[(koct * 8 + 5) * 33 + f]);
            o.w = pk2(Ltr[(koct * 8 + 6) * 33 + f], Ltr[(koct * 8 + 7) * 33 + f]);
            *(uint4*)(f1F + ((((size_t)es * 2 + nt) * 32 + kslice) * 64 + lane2) * 8) = o;
        }
    } else {
        float* Ltr = smem;   // [64][33]
        const int i2 = blockIdx.x - 768;
        const int es = i2 >> 2;
        const int dq = i2 & 3;
        for (int d0 = dq * 256; d0 < dq * 256 + 256; d0 += 64) {
            const int f = t >> 3, ds = (t & 7) * 8;
            const float* src = f2 + (size_t)es * (FF * DM) + f * DM + d0 + ds;
            float4 a = *(const float4*)src;
            float4 b = *(const float4*)(src + 4);
            __syncthreads();
            Ltr[(ds + 0) * 33 + f] = a.x; Ltr[(ds + 1) * 33 + f] = a.y;
            Ltr[(ds + 2) * 33 + f] = a.z; Ltr[(ds + 3) * 33 + f] = a.w;
            Ltr[(ds + 4) * 33 + f] = b.x; Ltr[(ds + 5) * 33 + f] = b.y;
            Ltr[(ds + 6) * 33 + f] = b.z; Ltr[(ds + 7) * 33 + f] = b.w;
            __syncthreads();
            const int dd = t >> 2, f0 = (t & 3) * 8;
            uint4 o;
            o.x = pk2(Ltr[dd * 33 + f0 + 0], Ltr[dd * 33 + f0 + 1]);
            o.y = pk2(Ltr[dd * 33 + f0 + 2], Ltr[dd * 33 + f0 + 3]);
            o.z = pk2(Ltr[dd * 33 + f0 + 4], Ltr[dd * 33 + f0 + 5]);
            o.w = pk2(Ltr[dd * 33 + f0 + 6], Ltr[dd * 33 + f0 + 7]);
            *(uint4*)(f2T + (size_t)es * (FF * DM) + (d0 + dd) * FF + f0) = o;
        }
    }
}

// ---------------------------------------------------------------------------
// K2: H = relu(x_gathered @ f1 + bias) via MFMA. LDS-free. UNCHANGED.
// ---------------------------------------------------------------------------
__global__ __launch_bounds__(256) void k_h_mfma(
    const ushort* __restrict__ xb, const ushort* __restrict__ f1F,
    const float* __restrict__ bias, const int* __restrict__ idx,
    ushort* __restrict__ Hb)
{
    const int es = blockIdx.x >> 2;
    const int gq = blockIdx.x & 3;
    const int w = threadIdx.x >> 6;
    const int lane = threadIdx.x & 63;
    const int lrow = lane & 15;
    const int lk8 = (lane >> 4) * 8;

    const int ga = gq * 64 + w * 16 + lrow;
    const int tok = idx[ga * NSLOT + es];
    const ushort* abase = xb + ((size_t)ga * TG + tok) * DM + lk8;
    const ushort* bbase = f1F + (size_t)es * 2 * 32 * 512 + (size_t)lane * 8;

    f32x4 acc[2] = {(f32x4){0.f, 0.f, 0.f, 0.f}, (f32x4){0.f, 0.f, 0.f, 0.f}};

#pragma unroll 4
    for (int kslice = 0; kslice < 32; ++kslice) {
        const bf16x8 A = *(const bf16x8*)(abase + kslice * 32);
#pragma unroll
        for (int nt = 0; nt < 2; ++nt) {
            const bf16x8 B = *(const bf16x8*)(bbase + ((size_t)nt * 32 + kslice) * 512);
            acc[nt] = __builtin_amdgcn_mfma_f32_16x16x32_bf16(A, B, acc[nt], 0, 0, 0);
        }
    }

#pragma unroll
    for (int nt = 0; nt < 2; ++nt) {
        const int f = nt * 16 + lrow;
        const float bv = bias[es * FF + f];
#pragma unroll
        for (int r = 0; r < 4; ++r) {
            const int g = gq * 64 + w * 16 + (lane >> 4) * 4 + r;
            const float hv = fmaxf(acc[nt][r] + bv, 0.0f);
            Hb[(size_t)g * (NSLOT * FF) + es * FF + f] = f2bf(hv);
        }
    }
}

// ---------------------------------------------------------------------------
// K3 (v16): v14's bank-correct 4-group geometry (80 KB -> 2 blocks/CU,
// 0 LDS conflicts) with the ONE variable that broke v14 reverted:
// grid mapping back to v13's proven db-MINOR order:
//   D0 = (bid & 15) * 64, G0 = (bid >> 4) * 4
// (v14's db-major made each XCD cache 4 MB of f2T slabs + 2 MB Hb -> thrash,
//  FETCH 35 MB; db-minor keeps the resident-set sweep compulsory ~13 MB.)
// ---------------------------------------------------------------------------
__global__ __launch_bounds__(256) void k_out_mfma(
    const ushort* __restrict__ Hb, const ushort* __restrict__ f2T,
    const uchar* __restrict__ idx8, float* __restrict__ out)
{
    extern __shared__ char smK3[];
    float* OL  = (float*)smK3;                 // [32t][64 16B-slots] = 32 KB
    char*  Bf  = smK3 + 32768;                 // [512][4 g] 16B     = 32 KB
    char*  Ring = smK3 + 65536;                // [4 w][4 slots][1024] = 16 KB

    const int D0 = (blockIdx.x & 15) * 64;     // db MINOR (v13 order)
    const int G0 = (blockIdx.x >> 4) * 4;
    const int tid = threadIdx.x;
    const int w = tid >> 6;
    const int lane = tid & 63;
    const int gl = lane & 15;
    const int g4 = gl & 3;
    const int sq = lane >> 4;
    const int lk8 = sq * 8;

    // zero OL (8192 f32)
    for (int i = tid * 4; i < 8192; i += 1024)
        *(f32x4*)&OL[i] = (f32x4){0.f, 0.f, 0.f, 0.f};
    // stage Bf: linear slot i = es*16 + bs*4 + bg  <- Hb[G0+bg][es*32 + bs*8]
#pragma unroll
    for (int it = 0; it < 8; ++it) {
        const int i = tid + it * 256;
        const int bg = i & 3, bs = (i >> 2) & 3, be = i >> 4;
        const uint4 q = *(const uint4*)(
            Hb + (size_t)(G0 + bg) * (NSLOT * FF) + be * FF + bs * 8);
        *(uint4*)(Bf + i * 16) = q;
    }
    // idx8 preload: this lane's group row (128 bytes -> 32 regs)
    uint ui[32];
    {
        const uint4* p = (const uint4*)(idx8 + (size_t)(G0 + g4) * NSLOT);
#pragma unroll
        for (int k = 0; k < 8; ++k) {
            const uint4 v = p[k];
            ui[k * 4 + 0] = v.x; ui[k * 4 + 1] = v.y;
            ui[k * 4 + 2] = v.z; ui[k * 4 + 3] = v.w;
        }
    }
    __syncthreads();

    // per-lane A source: d-row = D0 + w*16 + gl, f-offset lk8 (16B)
    const ushort* ap = f2T + (size_t)(D0 + w * 16 + gl) * FF + lk8;
    char* ring = Ring + w * 4096;

    // prologue: stage es 0..2
#pragma unroll
    for (int s = 0; s < 3; ++s)
        gload_lds16(ap + (size_t)s * (FF * DM), ring + s * 1024);

    const int q4 = (w * 4 + sq) * 4 + g4;   // OL 16B-slot within t-row

#pragma unroll
    for (int e = 0; e < 128; ++e) {
        gload_lds16(ap + (size_t)((e + 3) & 127) * (FF * DM),
                    ring + ((e + 3) & 3) * 1024);
        asm volatile("s_waitcnt vmcnt(3)" ::: "memory");   // es e staged

        const bf16x8 afr = *(const bf16x8*)(ring + (e & 3) * 1024 + lane * 16);
        const bf16x8 bfr = *(const bf16x8*)(Bf + ((e * 4 + sq) * 4 + g4) * 16);
        const f32x4 d = __builtin_amdgcn_mfma_f32_16x16x32_bf16(
            afr, bfr, (f32x4){0.f, 0.f, 0.f, 0.f}, 0, 0, 0);
        const uint tv = (ui[e >> 2] >> ((e & 3) * 8)) & 0xFFu;
        float* olp = &OL[tv * 256 + q4 * 4];
        *(f32x4*)olp = *(const f32x4*)olp + d;
    }
    asm volatile("s_waitcnt vmcnt(0)" ::: "memory");
    __syncthreads();

    // epilogue: slot i = t*64 + q*4 + g -> out[(G0+g)*TG + t][D0 + q*4 ..]
#pragma unroll
    for (int it = 0; it < 8; ++it) {
        const int i = tid + it * 256;
        const int t = i >> 6, rem = i & 63;
        const int q = rem >> 2, g = rem & 3;
        const f32x4 v = *(const f32x4*)&OL[i * 4];
        *(f32x4*)&out[((size_t)(G0 + g) * TG + t) * DM + D0 + q * 4] = v;
    }
}

// ---------------------------------------------------------------------------
extern "C" void kernel_launch(void* const* d_in, const int* in_sizes, int n_in,
                              void* d_out, int out_size, void* d_ws, size_t ws_size,
                              hipStream_t stream) {
    (void)in_sizes; (void)n_in; (void)out_size; (void)ws_size;
    const float* x    = (const float*)d_in[0];
    const float* ctrl = (const float*)d_in[1];
    const float* f1   = (const float*)d_in[2];
    const float* bias = (const float*)d_in[3];
    const float* f2   = (const float*)d_in[4];
    float* out = (float*)d_out;

    char* ws = (char*)d_ws;
    int*    idx  = (int*)ws;                        // 128 KB
    ushort* Hb   = (ushort*)(ws + 131072);          // 2 MB
    ushort* f1F  = (ushort*)(ws + 2228224);         // 8 MB
    ushort* f2T  = (ushort*)(ws + 10616832);        // 8 MB
    ushort* xb   = (ushort*)(ws + 19005440);        // 16 MB
    uchar*  idx8 = (uchar*)(ws + 35782656);         // 32 KB (end ~34.2 MB)

    k_fused1<<<1280, 256, 0, stream>>>(x, ctrl, f1, f2, idx, idx8, xb, f1F, f2T);

    k_h_mfma<<<NSLOT * 4, 256, 0, stream>>>(xb, f1F, bias, idx, Hb);

    const size_t lds3 = 81920;                      // 80 KB -> 2 blocks/CU
    hipFuncSetAttribute((const void*)k_out_mfma,
                        hipFuncAttributeMaxDynamicSharedMemorySize, (int)lds3);
    k_out_mfma<<<16 * 64, 256, lds3, stream>>>(Hb, f2T, idx8, out);
}

// Round 17
// 85.448 us; speedup vs baseline: 1.0891x; 1.0891x over previous
//
#include <hip/hip_runtime.h>
#include <hip/hip_bf16.h>

#define NGROUP 256   // B * (SEQ/TG)
#define NSLOT  128   // experts * sets
#define TG     32    // tokens per group
#define DM     1024  // model dim
#define FF     32    // expert size

#define LSCALE     4096.0f
#define INV_LSCALE (1.0f / 4096.0f)

typedef unsigned int  uint;
typedef unsigned short ushort;
typedef unsigned char uchar;
typedef __attribute__((ext_vector_type(4))) float f32x4;
typedef __attribute__((ext_vector_type(8))) short bf16x8;
typedef __attribute__((ext_vector_type(8))) _Float16 f16x8;

__device__ __forceinline__ ushort f2bf(float f) {
    uint u = __float_as_uint(f);
    u += 0x7FFFu + ((u >> 16) & 1u);   // RNE
    return (ushort)(u >> 16);
}
__device__ __forceinline__ uint pk2(float a, float b) {
    return (uint)f2bf(a) | ((uint)f2bf(b) << 16);
}

// async global->LDS, 16B per lane; dst wave-uniform base (+lane*16 implicit)
__device__ __forceinline__ void gload_lds16(const void* g, void* l) {
    __builtin_amdgcn_global_load_lds(
        (const __attribute__((address_space(1))) uint*)g,
        (__attribute__((address_space(3))) uint*)l, 16, 0, 0);
}

// ---------------------------------------------------------------------------
// K1 mega-kernel (v9-proven, UNCHANGED): one launch, three block families.
//  blocks 0..511    : logits + tie-broken argmax + fused x->bf16 cast (+idx8)
//  blocks 512..767  : f1 -> f1F bf16 (MFMA-B fragment order)
//  blocks 768..1279 : f2 -> f2T[es][d][f] bf16
// ---------------------------------------------------------------------------
__global__ __launch_bounds__(256) void k_fused1(
    const float* __restrict__ x, const float* __restrict__ ctrl,
    const float* __restrict__ f1, const float* __restrict__ f2,
    int* __restrict__ idx, uchar* __restrict__ idx8, ushort* __restrict__ xb,
    ushort* __restrict__ f1F, ushort* __restrict__ f2T)
{
    __shared__ float smem[4 * 32 * 64];   // 32 KB
    const int t = threadIdx.x;

    if (blockIdx.x < 512) {
        float* Lp = smem;
        const int g  = blockIdx.x >> 1;
        const int nh = blockIdx.x & 1;
        const int w = t >> 6;
        const int lane = t & 63;
        const int lrow = lane & 15;
        const int lk8 = (lane >> 4) * 8;

        const size_t xoff0 = ((size_t)g * TG + lrow) * DM + w * 256 + lk8;
        const float* xr0 = x + xoff0;
        const float* xr1 = xr0 + 16 * DM;

        f32x4 ahh[2][4], ax[2][4];
#pragma unroll
        for (int mt = 0; mt < 2; ++mt)
#pragma unroll
            for (int nt = 0; nt < 4; ++nt) {
                ahh[mt][nt] = (f32x4){0.f, 0.f, 0.f, 0.f};
                ax[mt][nt]  = (f32x4){0.f, 0.f, 0.f, 0.f};
            }

        for (int ks = 0; ks < 8; ++ks) {
            f16x8 Ah[2], Al[2];
#pragma unroll
            for (int mt = 0; mt < 2; ++mt) {
                const float* p = (mt ? xr1 : xr0) + ks * 32;
                float xe[8];
                *(float4*)&xe[0] = *(const float4*)p;
                *(float4*)&xe[4] = *(const float4*)(p + 4);
                union { f16x8 v; _Float16 e[8]; } H, L;
#pragma unroll
                for (int j = 0; j < 8; ++j) {
                    const _Float16 h = (_Float16)xe[j];
                    H.e[j] = h;
                    L.e[j] = (_Float16)((xe[j] - (float)h) * LSCALE);
                }
                Ah[mt] = H.v; Al[mt] = L.v;
                if (nh == 0) {
                    uint4 o;
                    o.x = pk2(xe[0], xe[1]); o.y = pk2(xe[2], xe[3]);
                    o.z = pk2(xe[4], xe[5]); o.w = pk2(xe[6], xe[7]);
                    *(uint4*)(xb + xoff0 + (size_t)mt * 16 * DM + ks * 32) = o;
                }
            }
            const int kslice = w * 8 + ks;
#pragma unroll
            for (int nt = 0; nt < 4; ++nt) {
                const float* cp = ctrl
                    + (size_t)(kslice * 32 + ((lane >> 4) << 3)) * NSLOT
                    + nh * 64 + nt * 16 + (lane & 15);
                union { f16x8 v; _Float16 e[8]; } BH, BL;
#pragma unroll
                for (int j = 0; j < 8; ++j) {
                    const float c = cp[(size_t)j * NSLOT];
                    const _Float16 h = (_Float16)c;
                    BH.e[j] = h;
                    BL.e[j] = (_Float16)((c - (float)h) * LSCALE);
                }
#pragma unroll
                for (int mt = 0; mt < 2; ++mt) {
                    ahh[mt][nt] = __builtin_amdgcn_mfma_f32_16x16x32_f16(Ah[mt], BH.v, ahh[mt][nt], 0, 0, 0);
                    ax[mt][nt]  = __builtin_amdgcn_mfma_f32_16x16x32_f16(Al[mt], BH.v, ax[mt][nt], 0, 0, 0);
                    ax[mt][nt]  = __builtin_amdgcn_mfma_f32_16x16x32_f16(Ah[mt], BL.v, ax[mt][nt], 0, 0, 0);
                }
            }
        }

#pragma unroll
        for (int mt = 0; mt < 2; ++mt)
#pragma unroll
            for (int nt = 0; nt < 4; ++nt)
#pragma unroll
                for (int r = 0; r < 4; ++r) {
                    const int trow = mt * 16 + (lane >> 4) * 4 + r;
                    const int nl = nt * 16 + lrow;
                    Lp[(w * TG + trow) * 64 + nl] =
                        ahh[mt][nt][r] + ax[mt][nt][r] * INV_LSCALE;
                }
        __syncthreads();

        for (int i = t * 4; i < TG * 64; i += 256 * 4) {
            f32x4 s0 = *(const f32x4*)&Lp[i];
            f32x4 s1 = *(const f32x4*)&Lp[2048 + i];
            f32x4 s2 = *(const f32x4*)&Lp[4096 + i];
            f32x4 s3 = *(const f32x4*)&Lp[6144 + i];
            *(f32x4*)&Lp[i] = (s0 + s1) + (s2 + s3);
        }
        __syncthreads();

        if (t < 64) {
            const int n = t;
            float best = -1e30f;
            int bi = 0;
#pragma unroll
            for (int tt = 0; tt < TG; ++tt) {
                const float v = Lp[tt * 64 + n] + (float)tt * (1e-6f / 31.0f);
                if (v >= best) { best = v; bi = tt; }   // later token wins ties
            }
            idx[g * NSLOT + nh * 64 + n] = bi;
            idx8[g * NSLOT + nh * 64 + n] = (uchar)bi;
        }
    } else if (blockIdx.x < 768) {
        float* Ltr = smem;   // [64][33]
        const int i1 = blockIdx.x - 512;
        const int es = i1 >> 1;
        const int dh = i1 & 1;
        for (int d0 = dh * 512; d0 < dh * 512 + 512; d0 += 64) {
            const int dd = t >> 2, f0 = (t & 3) * 8;
            const float* src = f1 + (size_t)(d0 + dd) * 4096 + es * FF + f0;
            float4 a = *(const float4*)src;
            float4 b = *(const float4*)(src + 4);
            __syncthreads();
            float* Lq = &Ltr[dd * 33 + f0];
            Lq[0] = a.x; Lq[1] = a.y; Lq[2] = a.z; Lq[3] = a.w;
            Lq[4] = b.x; Lq[5] = b.y; Lq[6] = b.z; Lq[7] = b.w;
            __syncthreads();
            const int f = t & 31, koct = t >> 5;
            const int nt = f >> 4;
            const int kg = d0 + koct * 8;
            const int kslice = kg >> 5;
            const int lane2 = (f & 15) | (((kg >> 3) & 3) << 4);
            uint4 o;
            o.x = pk2(Ltr[(koct * 8 + 0) * 33 + f], Ltr[(koct * 8 + 1) * 33 + f]);
            o.y = pk2(Ltr[(koct * 8 + 2) * 33 + f], Ltr[(koct * 8 + 3) * 33 + f]);
            o.z = pk2(Ltr[(koct * 8 + 4) * 33 + f], Ltr[(koct * 8 + 5) * 33 + f]);
            o.w = pk2(Ltr[(koct * 8 + 6) * 33 + f], Ltr[(koct * 8 + 7) * 33 + f]);
            *(uint4*)(f1F + ((((size_t)es * 2 + nt) * 32 + kslice) * 64 + lane2) * 8) = o;
        }
    } else {
        float* Ltr = smem;   // [64][33]
        const int i2 = blockIdx.x - 768;
        const int es = i2 >> 2;
        const int dq = i2 & 3;
        for (int d0 = dq * 256; d0 < dq * 256 + 256; d0 += 64) {
            const int f = t >> 3, ds = (t & 7) * 8;
            const float* src = f2 + (size_t)es * (FF * DM) + f * DM + d0 + ds;
            float4 a = *(const float4*)src;
            float4 b = *(const float4*)(src + 4);
            __syncthreads();
            Ltr[(ds + 0) * 33 + f] = a.x; Ltr[(ds + 1) * 33 + f] = a.y;
            Ltr[(ds + 2) * 33 + f] = a.z; Ltr[(ds + 3) * 33 + f] = a.w;
            Ltr[(ds + 4) * 33 + f] = b.x; Ltr[(ds + 5) * 33 + f] = b.y;
            Ltr[(ds + 6) * 33 + f] = b.z; Ltr[(ds + 7) * 33 + f] = b.w;
            __syncthreads();
            const int dd = t >> 2, f0 = (t & 3) * 8;
            uint4 o;
            o.x = pk2(Ltr[dd * 33 + f0 + 0], Ltr[dd * 33 + f0 + 1]);
            o.y = pk2(Ltr[dd * 33 + f0 + 2], Ltr[dd * 33 + f0 + 3]);
            o.z = pk2(Ltr[dd * 33 + f0 + 4], Ltr[dd * 33 + f0 + 5]);
            o.w = pk2(Ltr[dd * 33 + f0 + 6], Ltr[dd * 33 + f0 + 7]);
            *(uint4*)(f2T + (size_t)es * (FF * DM) + (d0 + dd) * FF + f0) = o;
        }
    }
}

// ---------------------------------------------------------------------------
// K2: H = relu(x_gathered @ f1 + bias) via MFMA. LDS-free. UNCHANGED.
// ---------------------------------------------------------------------------
__global__ __launch_bounds__(256) void k_h_mfma(
    const ushort* __restrict__ xb, const ushort* __restrict__ f1F,
    const float* __restrict__ bias, const int* __restrict__ idx,
    ushort* __restrict__ Hb)
{
    const int es = blockIdx.x >> 2;
    const int gq = blockIdx.x & 3;
    const int w = threadIdx.x >> 6;
    const int lane = threadIdx.x & 63;
    const int lrow = lane & 15;
    const int lk8 = (lane >> 4) * 8;

    const int ga = gq * 64 + w * 16 + lrow;
    const int tok = idx[ga * NSLOT + es];
    const ushort* abase = xb + ((size_t)ga * TG + tok) * DM + lk8;
    const ushort* bbase = f1F + (size_t)es * 2 * 32 * 512 + (size_t)lane * 8;

    f32x4 acc[2] = {(f32x4){0.f, 0.f, 0.f, 0.f}, (f32x4){0.f, 0.f, 0.f, 0.f}};

#pragma unroll 4
    for (int kslice = 0; kslice < 32; ++kslice) {
        const bf16x8 A = *(const bf16x8*)(abase + kslice * 32);
#pragma unroll
        for (int nt = 0; nt < 2; ++nt) {
            const bf16x8 B = *(const bf16x8*)(bbase + ((size_t)nt * 32 + kslice) * 512);
            acc[nt] = __builtin_amdgcn_mfma_f32_16x16x32_bf16(A, B, acc[nt], 0, 0, 0);
        }
    }

#pragma unroll
    for (int nt = 0; nt < 2; ++nt) {
        const int f = nt * 16 + lrow;
        const float bv = bias[es * FF + f];
#pragma unroll
        for (int r = 0; r < 4; ++r) {
            const int g = gq * 64 + w * 16 + (lane >> 4) * 4 + r;
            const float hv = fmaxf(acc[nt][r] + bv, 0.0f);
            Hb[(size_t)g * (NSLOT * FF) + es * FF + f] = f2bf(hv);
        }
    }
}

// ---------------------------------------------------------------------------
// K3 (v17): v13 structure with ring depth 3 -> 7 chunks. Bfull deleted; B is
// staged through the ring alongside A (per 2-es chunk: A es0 1KB + A es1 1KB
// + B-pair 1KB, per-lane-permuted source so the linear LDS dest matches the
// consumer layout). Ring = 4 waves x 8 slots x 3KB = 96 KB; OL = 64 KB;
// total = 160 KiB exactly. Prologue stages 7 chunks (21 loads); main loop
// issues chunk c+7 then waits vmcnt(21) -> cover ~7 iterations >> latency.
// Per-wave es order identical to v13 -> output bit-identical.
// ---------------------------------------------------------------------------
__global__ __launch_bounds__(256) void k_out_mfma(
    const ushort* __restrict__ Hb, const ushort* __restrict__ f2T,
    const uchar* __restrict__ idx8, float* __restrict__ out)
{
    extern __shared__ char smK3[];
    float* OL   = (float*)smK3;                // [8][2048] f32, quad-swizzled
    char*  Ring = smK3 + 65536;                // [4 w][8 slots][3072 B]

    const int db = blockIdx.x & 15;            // db-minor (proven v13 order)
    const int go = blockIdx.x >> 4;
    const int G0 = go * 8;
    const int D0 = db * 64;
    const int tid = threadIdx.x;
    const int w = tid >> 6;
    const int lane = tid & 63;
    const int gl = lane & 15;
    const int g8 = gl & 7;
    const int sq = lane >> 4;                  // 0..3
    const int lk8 = sq * 8;

    // zero OL
    for (int i = tid * 4; i < 8 * 2048; i += 1024)
        *(f32x4*)&OL[i] = (f32x4){0.f, 0.f, 0.f, 0.f};
    // preload idx8 row for this lane's group: 128 bytes -> 32 regs
    uint ui[32];
    {
        const uint4* p = (const uint4*)(idx8 + (size_t)(G0 + g8) * NSLOT);
#pragma unroll
        for (int k = 0; k < 8; ++k) {
            const uint4 v = p[k];
            ui[k * 4 + 0] = v.x; ui[k * 4 + 1] = v.y;
            ui[k * 4 + 2] = v.z; ui[k * 4 + 3] = v.w;
        }
    }
    __syncthreads();

    // A source: per-lane, d-row = D0 + w*16 + gl, f-slice lk8
    const ushort* ap = f2T + (size_t)(D0 + w * 16 + gl) * FF + lk8;
    // B source: lane l stages slot l = (eo = l>>5, bsq = (l>>3)&3, bg = l&7):
    //   Hb[G0+bg][ (2c+eo)*32 + bsq*8 .. +8 )
    const int beo = lane >> 5, bsq = (lane >> 3) & 3, bg = lane & 7;
    const ushort* bps = Hb + (size_t)(G0 + bg) * (NSLOT * FF) + beo * FF + bsq * 8;
    char* ring = Ring + w * 24576;

    // prologue: stage chunks 0..6 (3 loads each = 21 outstanding)
#pragma unroll
    for (int s = 0; s < 7; ++s) {
        char* slot = ring + s * 3072;
        gload_lds16(ap + (size_t)(2 * s)     * (FF * DM), slot);
        gload_lds16(ap + (size_t)(2 * s + 1) * (FF * DM), slot + 1024);
        gload_lds16(bps + (size_t)(2 * s) * FF,           slot + 2048);
    }

    float* olrow = &OL[g8 * 2048];
    const int qbase = w * 4 + sq;

#pragma unroll
    for (int c = 0; c < 64; ++c) {
        // issue chunk c+7 (wraps to restage chunks 0..6 at tail; dummies)
        {
            const int cn = (c + 7) & 63;
            char* slot = ring + ((c + 7) & 7) * 3072;
            gload_lds16(ap + (size_t)(2 * cn)     * (FF * DM), slot);
            gload_lds16(ap + (size_t)(2 * cn + 1) * (FF * DM), slot + 1024);
            gload_lds16(bps + (size_t)(2 * cn) * FF,           slot + 2048);
        }
        asm volatile("s_waitcnt vmcnt(21)" ::: "memory");   // chunk c ready

        const char* slot = ring + (c & 7) * 3072;
#pragma unroll
        for (int h = 0; h < 2; ++h) {
            const int e = c * 2 + h;
            const bf16x8 afr = *(const bf16x8*)(slot + h * 1024 + lane * 16);
            const bf16x8 bfr = *(const bf16x8*)(slot + 2048 + (h * 32 + sq * 8 + g8) * 16);
            const f32x4 d = __builtin_amdgcn_mfma_f32_16x16x32_bf16(
                afr, bfr, (f32x4){0.f, 0.f, 0.f, 0.f}, 0, 0, 0);
            const uint tv = (ui[e >> 2] >> ((e & 3) * 8)) & 0xFFu;
            const int q = (int)tv * 16 + qbase;
            float* olp = olrow + ((q ^ g8) << 2);
            *(f32x4*)olp = *(const f32x4*)olp + d;
        }
    }
    asm volatile("s_waitcnt vmcnt(0)" ::: "memory");
    __syncthreads();

    // dense write-out: logical (gli, t, d) from physical quad (q ^ gli)
    for (int it = 0; it < 16; ++it) {
        const int flat = tid * 4 + it * 1024;
        const int gli = flat >> 11, rem = flat & 2047;
        const int t = rem >> 6, d = rem & 63;
        const int q = rem >> 2;
        const f32x4 v = *(const f32x4*)&OL[gli * 2048 + ((q ^ gli) << 2)];
        *(f32x4*)&out[((size_t)(G0 + gli) * TG + t) * DM + D0 + d] = v;
    }
}

// ---------------------------------------------------------------------------
extern "C" void kernel_launch(void* const* d_in, const int* in_sizes, int n_in,
                              void* d_out, int out_size, void* d_ws, size_t ws_size,
                              hipStream_t stream) {
    (void)in_sizes; (void)n_in; (void)out_size; (void)ws_size;
    const float* x    = (const float*)d_in[0];
    const float* ctrl = (const float*)d_in[1];
    const float* f1   = (const float*)d_in[2];
    const float* bias = (const float*)d_in[3];
    const float* f2   = (const float*)d_in[4];
    float* out = (float*)d_out;

    char* ws = (char*)d_ws;
    int*    idx  = (int*)ws;                        // 128 KB
    ushort* Hb   = (ushort*)(ws + 131072);          // 2 MB
    ushort* f1F  = (ushort*)(ws + 2228224);         // 8 MB
    ushort* f2T  = (ushort*)(ws + 10616832);        // 8 MB
    ushort* xb   = (ushort*)(ws + 19005440);        // 16 MB
    uchar*  idx8 = (uchar*)(ws + 35782656);         // 32 KB (end ~34.2 MB)

    k_fused1<<<1280, 256, 0, stream>>>(x, ctrl, f1, f2, idx, idx8, xb, f1F, f2T);

    k_h_mfma<<<NSLOT * 4, 256, 0, stream>>>(xb, f1F, bias, idx, Hb);

    const size_t lds3 = 163840;                     // 160 KiB exactly
    hipFuncSetAttribute((const void*)k_out_mfma,
                        hipFuncAttributeMaxDynamicSharedMemorySize, (int)lds3);
    k_out_mfma<<<512, 256, lds3, stream>>>(Hb, f2T, idx8, out);
}

// Round 18
// 75.197 us; speedup vs baseline: 1.2376x; 1.1363x over previous
//
#include <hip/hip_runtime.h>
#include <hip/hip_bf16.h>

#define NGROUP 256   // B * (SEQ/TG)
#define NSLOT  128   // experts * sets
#define TG     32    // tokens per group
#define DM     1024  // model dim
#define FF     32    // expert size

#define LSCALE     4096.0f
#define INV_LSCALE (1.0f / 4096.0f)

typedef unsigned int  uint;
typedef unsigned short ushort;
typedef unsigned char uchar;
typedef __attribute__((ext_vector_type(4))) float f32x4;
typedef __attribute__((ext_vector_type(8))) short bf16x8;
typedef __attribute__((ext_vector_type(8))) _Float16 f16x8;

__device__ __forceinline__ ushort f2bf(float f) {
    uint u = __float_as_uint(f);
    u += 0x7FFFu + ((u >> 16) & 1u);   // RNE
    return (ushort)(u >> 16);
}
__device__ __forceinline__ uint pk2(float a, float b) {
    return (uint)f2bf(a) | ((uint)f2bf(b) << 16);
}

// async global->LDS, 16B per lane; dst wave-uniform base (+lane*16 implicit)
__device__ __forceinline__ void gload_lds16(const void* g, void* l) {
    __builtin_amdgcn_global_load_lds(
        (const __attribute__((address_space(1))) uint*)g,
        (__attribute__((address_space(3))) uint*)l, 16, 0, 0);
}

// ---------------------------------------------------------------------------
// K1 mega-kernel (v9-proven, UNCHANGED): one launch, three block families.
//  blocks 0..511    : logits + tie-broken argmax + fused x->bf16 cast (+idx8)
//  blocks 512..767  : f1 -> f1F bf16 (MFMA-B fragment order)
//  blocks 768..1279 : f2 -> f2T[es][d][f] bf16
// ---------------------------------------------------------------------------
__global__ __launch_bounds__(256) void k_fused1(
    const float* __restrict__ x, const float* __restrict__ ctrl,
    const float* __restrict__ f1, const float* __restrict__ f2,
    int* __restrict__ idx, uchar* __restrict__ idx8, ushort* __restrict__ xb,
    ushort* __restrict__ f1F, ushort* __restrict__ f2T)
{
    __shared__ float smem[4 * 32 * 64];   // 32 KB
    const int t = threadIdx.x;

    if (blockIdx.x < 512) {
        float* Lp = smem;
        const int g  = blockIdx.x >> 1;
        const int nh = blockIdx.x & 1;
        const int w = t >> 6;
        const int lane = t & 63;
        const int lrow = lane & 15;
        const int lk8 = (lane >> 4) * 8;

        const size_t xoff0 = ((size_t)g * TG + lrow) * DM + w * 256 + lk8;
        const float* xr0 = x + xoff0;
        const float* xr1 = xr0 + 16 * DM;

        f32x4 ahh[2][4], ax[2][4];
#pragma unroll
        for (int mt = 0; mt < 2; ++mt)
#pragma unroll
            for (int nt = 0; nt < 4; ++nt) {
                ahh[mt][nt] = (f32x4){0.f, 0.f, 0.f, 0.f};
                ax[mt][nt]  = (f32x4){0.f, 0.f, 0.f, 0.f};
            }

        for (int ks = 0; ks < 8; ++ks) {
            f16x8 Ah[2], Al[2];
#pragma unroll
            for (int mt = 0; mt < 2; ++mt) {
                const float* p = (mt ? xr1 : xr0) + ks * 32;
                float xe[8];
                *(float4*)&xe[0] = *(const float4*)p;
                *(float4*)&xe[4] = *(const float4*)(p + 4);
                union { f16x8 v; _Float16 e[8]; } H, L;
#pragma unroll
                for (int j = 0; j < 8; ++j) {
                    const _Float16 h = (_Float16)xe[j];
                    H.e[j] = h;
                    L.e[j] = (_Float16)((xe[j] - (float)h) * LSCALE);
                }
                Ah[mt] = H.v; Al[mt] = L.v;
                if (nh == 0) {
                    uint4 o;
                    o.x = pk2(xe[0], xe[1]); o.y = pk2(xe[2], xe[3]);
                    o.z = pk2(xe[4], xe[5]); o.w = pk2(xe[6], xe[7]);
                    *(uint4*)(xb + xoff0 + (size_t)mt * 16 * DM + ks * 32) = o;
                }
            }
            const int kslice = w * 8 + ks;
#pragma unroll
            for (int nt = 0; nt < 4; ++nt) {
                const float* cp = ctrl
                    + (size_t)(kslice * 32 + ((lane >> 4) << 3)) * NSLOT
                    + nh * 64 + nt * 16 + (lane & 15);
                union { f16x8 v; _Float16 e[8]; } BH, BL;
#pragma unroll
                for (int j = 0; j < 8; ++j) {
                    const float c = cp[(size_t)j * NSLOT];
                    const _Float16 h = (_Float16)c;
                    BH.e[j] = h;
                    BL.e[j] = (_Float16)((c - (float)h) * LSCALE);
                }
#pragma unroll
                for (int mt = 0; mt < 2; ++mt) {
                    ahh[mt][nt] = __builtin_amdgcn_mfma_f32_16x16x32_f16(Ah[mt], BH.v, ahh[mt][nt], 0, 0, 0);
                    ax[mt][nt]  = __builtin_amdgcn_mfma_f32_16x16x32_f16(Al[mt], BH.v, ax[mt][nt], 0, 0, 0);
                    ax[mt][nt]  = __builtin_amdgcn_mfma_f32_16x16x32_f16(Ah[mt], BL.v, ax[mt][nt], 0, 0, 0);
                }
            }
        }

#pragma unroll
        for (int mt = 0; mt < 2; ++mt)
#pragma unroll
            for (int nt = 0; nt < 4; ++nt)
#pragma unroll
                for (int r = 0; r < 4; ++r) {
                    const int trow = mt * 16 + (lane >> 4) * 4 + r;
                    const int nl = nt * 16 + lrow;
                    Lp[(w * TG + trow) * 64 + nl] =
                        ahh[mt][nt][r] + ax[mt][nt][r] * INV_LSCALE;
                }
        __syncthreads();

        for (int i = t * 4; i < TG * 64; i += 256 * 4) {
            f32x4 s0 = *(const f32x4*)&Lp[i];
            f32x4 s1 = *(const f32x4*)&Lp[2048 + i];
            f32x4 s2 = *(const f32x4*)&Lp[4096 + i];
            f32x4 s3 = *(const f32x4*)&Lp[6144 + i];
            *(f32x4*)&Lp[i] = (s0 + s1) + (s2 + s3);
        }
        __syncthreads();

        if (t < 64) {
            const int n = t;
            float best = -1e30f;
            int bi = 0;
#pragma unroll
            for (int tt = 0; tt < TG; ++tt) {
                const float v = Lp[tt * 64 + n] + (float)tt * (1e-6f / 31.0f);
                if (v >= best) { best = v; bi = tt; }   // later token wins ties
            }
            idx[g * NSLOT + nh * 64 + n] = bi;
            idx8[g * NSLOT + nh * 64 + n] = (uchar)bi;
        }
    } else if (blockIdx.x < 768) {
        float* Ltr = smem;   // [64][33]
        const int i1 = blockIdx.x - 512;
        const int es = i1 >> 1;
        const int dh = i1 & 1;
        for (int d0 = dh * 512; d0 < dh * 512 + 512; d0 += 64) {
            const int dd = t >> 2, f0 = (t & 3) * 8;
            const float* src = f1 + (size_t)(d0 + dd) * 4096 + es * FF + f0;
            float4 a = *(const float4*)src;
            float4 b = *(const float4*)(src + 4);
            __syncthreads();
            float* Lq = &Ltr[dd * 33 + f0];
            Lq[0] = a.x; Lq[1] = a.y; Lq[2] = a.z; Lq[3] = a.w;
            Lq[4] = b.x; Lq[5] = b.y; Lq[6] = b.z; Lq[7] = b.w;
            __syncthreads();
            const int f = t & 31, koct = t >> 5;
            const int nt = f >> 4;
            const int kg = d0 + koct * 8;
            const int kslice = kg >> 5;
            const int lane2 = (f & 15) | (((kg >> 3) & 3) << 4);
            uint4 o;
            o.x = pk2(Ltr[(koct * 8 + 0) * 33 + f], Ltr[(koct * 8 + 1) * 33 + f]);
            o.y = pk2(Ltr[(koct * 8 + 2) * 33 + f], Ltr[(koct * 8 + 3) * 33 + f]);
            o.z = pk2(Ltr[(koct * 8 + 4) * 33 + f], Ltr[(koct * 8 + 5) * 33 + f]);
            o.w = pk2(Ltr[(koct * 8 + 6) * 33 + f], Ltr[(koct * 8 + 7) * 33 + f]);
            *(uint4*)(f1F + ((((size_t)es * 2 + nt) * 32 + kslice) * 64 + lane2) * 8) = o;
        }
    } else {
        float* Ltr = smem;   // [64][33]
        const int i2 = blockIdx.x - 768;
        const int es = i2 >> 2;
        const int dq = i2 & 3;
        for (int d0 = dq * 256; d0 < dq * 256 + 256; d0 += 64) {
            const int f = t >> 3, ds = (t & 7) * 8;
            const float* src = f2 + (size_t)es * (FF * DM) + f * DM + d0 + ds;
            float4 a = *(const float4*)src;
            float4 b = *(const float4*)(src + 4);
            __syncthreads();
            Ltr[(ds + 0) * 33 + f] = a.x; Ltr[(ds + 1) * 33 + f] = a.y;
            Ltr[(ds + 2) * 33 + f] = a.z; Ltr[(ds + 3) * 33 + f] = a.w;
            Ltr[(ds + 4) * 33 + f] = b.x; Ltr[(ds + 5) * 33 + f] = b.y;
            Ltr[(ds + 6) * 33 + f] = b.z; Ltr[(ds + 7) * 33 + f] = b.w;
            __syncthreads();
            const int dd = t >> 2, f0 = (t & 3) * 8;
            uint4 o;
            o.x = pk2(Ltr[dd * 33 + f0 + 0], Ltr[dd * 33 + f0 + 1]);
            o.y = pk2(Ltr[dd * 33 + f0 + 2], Ltr[dd * 33 + f0 + 3]);
            o.z = pk2(Ltr[dd * 33 + f0 + 4], Ltr[dd * 33 + f0 + 5]);
            o.w = pk2(Ltr[dd * 33 + f0 + 6], Ltr[dd * 33 + f0 + 7]);
            *(uint4*)(f2T + (size_t)es * (FF * DM) + (d0 + dd) * FF + f0) = o;
        }
    }
}

// ---------------------------------------------------------------------------
// K2: H = relu(x_gathered @ f1 + bias) via MFMA. LDS-free. UNCHANGED.
// ---------------------------------------------------------------------------
__global__ __launch_bounds__(256) void k_h_mfma(
    const ushort* __restrict__ xb, const ushort* __restrict__ f1F,
    const float* __restrict__ bias, const int* __restrict__ idx,
    ushort* __restrict__ Hb)
{
    const int es = blockIdx.x >> 2;
    const int gq = blockIdx.x & 3;
    const int w = threadIdx.x >> 6;
    const int lane = threadIdx.x & 63;
    const int lrow = lane & 15;
    const int lk8 = (lane >> 4) * 8;

    const int ga = gq * 64 + w * 16 + lrow;
    const int tok = idx[ga * NSLOT + es];
    const ushort* abase = xb + ((size_t)ga * TG + tok) * DM + lk8;
    const ushort* bbase = f1F + (size_t)es * 2 * 32 * 512 + (size_t)lane * 8;

    f32x4 acc[2] = {(f32x4){0.f, 0.f, 0.f, 0.f}, (f32x4){0.f, 0.f, 0.f, 0.f}};

#pragma unroll 4
    for (int kslice = 0; kslice < 32; ++kslice) {
        const bf16x8 A = *(const bf16x8*)(abase + kslice * 32);
#pragma unroll
        for (int nt = 0; nt < 2; ++nt) {
            const bf16x8 B = *(const bf16x8*)(bbase + ((size_t)nt * 32 + kslice) * 512);
            acc[nt] = __builtin_amdgcn_mfma_f32_16x16x32_bf16(A, B, acc[nt], 0, 0, 0);
        }
    }

#pragma unroll
    for (int nt = 0; nt < 2; ++nt) {
        const int f = nt * 16 + lrow;
        const float bv = bias[es * FF + f];
#pragma unroll
        for (int r = 0; r < 4; ++r) {
            const int g = gq * 64 + w * 16 + (lane >> 4) * 4 + r;
            const float hv = fmaxf(acc[nt][r] + bv, 0.0f);
            Hb[(size_t)g * (NSLOT * FF) + es * FF + f] = f2bf(hv);
        }
    }
}

// ---------------------------------------------------------------------------
// K3 (v18): 16 DISTINCT groups x 64 d per block -> grid 256 = 1 block/CU,
// ONE round (v13 needed two). N=16 MFMA columns all useful (no dup).
//  - A ring: per-lane f2T source, linear dst (lane*16), 1 KB/es.
//  - B ring: per-lane Hb source ordered so dst lane*16 IS the consumer
//    fragment layout (col=lane&15 group, k-slice=lane>>4): 1 KB/es.
//  - Ring [4w][4 slots][2KB], distance 3, vmcnt(6).
//  - OL 128 KB: 16B-slot s=(dq<<4)|(dq^g) within each t-row -> RMW and
//    epilogue are <=2-way bank aliased (free). 64 distinct slots/wave-op.
//  - per-lane t from idx8 preloaded into 32 regs. es order per wave = v13.
// LDS = 131072 + 32768 = 163840 (160 KiB exactly).
// ---------------------------------------------------------------------------
__global__ __launch_bounds__(256) void k_out_mfma(
    const ushort* __restrict__ Hb, const ushort* __restrict__ f2T,
    const uchar* __restrict__ idx8, float* __restrict__ out)
{
    extern __shared__ char smK3[];
    float* OL   = (float*)smK3;                // [32 t][256 16B-slots] = 128 KB
    char*  Ring = smK3 + 131072;               // [4 w][4 slots][2048 B] = 32 KB

    const int D0 = (blockIdx.x & 15) * 64;     // db-minor (proven order)
    const int G0 = (blockIdx.x >> 4) * 16;
    const int tid = threadIdx.x;
    const int w = tid >> 6;
    const int lane = tid & 63;
    const int gl = lane & 15;                  // group (B col) AND A d-row
    const int sq = lane >> 4;                  // k-slice 0..3
    const int dq = w * 4 + sq;                 // d-quad 0..15

    // zero OL (32768 f32)
    for (int i = tid * 4; i < 32768; i += 1024)
        *(f32x4*)&OL[i] = (f32x4){0.f, 0.f, 0.f, 0.f};
    // preload idx8 row for this lane's group: 128 bytes -> 32 regs
    uint ui[32];
    {
        const uint4* p = (const uint4*)(idx8 + (size_t)(G0 + gl) * NSLOT);
#pragma unroll
        for (int k = 0; k < 8; ++k) {
            const uint4 v = p[k];
            ui[k * 4 + 0] = v.x; ui[k * 4 + 1] = v.y;
            ui[k * 4 + 2] = v.z; ui[k * 4 + 3] = v.w;
        }
    }
    __syncthreads();

    // per-lane sources
    const ushort* ap  = f2T + (size_t)(D0 + w * 16 + gl) * FF + sq * 8;
    const ushort* bps = Hb + (size_t)(G0 + gl) * (NSLOT * FF) + sq * 8;
    char* ring = Ring + w * 8192;

    // prologue: stage es 0..2 (A+B each -> 6 loads outstanding)
#pragma unroll
    for (int s = 0; s < 3; ++s) {
        gload_lds16(ap  + (size_t)s * (FF * DM), ring + s * 2048);
        gload_lds16(bps + (size_t)s * FF,        ring + s * 2048 + 1024);
    }

    const int sOL = (dq << 4) | (dq ^ gl);     // this lane's 16B slot in t-row

#pragma unroll 4
    for (int e = 0; e < 128; ++e) {
        // issue es e+3 (wraps at tail into already-consumed slots)
        {
            const int en = (e + 3) & 127;
            char* slot = ring + ((e + 3) & 3) * 2048;
            gload_lds16(ap  + (size_t)en * (FF * DM), slot);
            gload_lds16(bps + (size_t)en * FF,        slot + 1024);
        }
        asm volatile("s_waitcnt vmcnt(6)" ::: "memory");   // es e staged

        const char* slot = ring + (e & 3) * 2048;
        const bf16x8 afr = *(const bf16x8*)(slot + lane * 16);
        const bf16x8 bfr = *(const bf16x8*)(slot + 1024 + lane * 16);
        const f32x4 d = __builtin_amdgcn_mfma_f32_16x16x32_bf16(
            afr, bfr, (f32x4){0.f, 0.f, 0.f, 0.f}, 0, 0, 0);
        const uint tv = (ui[e >> 2] >> ((e & 3) * 8)) & 0xFFu;
        float* olp = &OL[tv * 1024 + sOL * 4];
        *(f32x4*)olp = *(const f32x4*)olp + d;
    }
    asm volatile("s_waitcnt vmcnt(0)" ::: "memory");
    __syncthreads();

    // epilogue: tid = g*16 + dq'; for each t write f32x4 (coalesced per g)
    {
        const int g = tid >> 4, dqe = tid & 15;
        const int se = (dqe << 4) | (dqe ^ g);
#pragma unroll 4
        for (int t = 0; t < TG; ++t) {
            const f32x4 v = *(const f32x4*)&OL[t * 1024 + se * 4];
            *(f32x4*)&out[((size_t)(G0 + g) * TG + t) * DM + D0 + dqe * 4] = v;
        }
    }
}

// ---------------------------------------------------------------------------
extern "C" void kernel_launch(void* const* d_in, const int* in_sizes, int n_in,
                              void* d_out, int out_size, void* d_ws, size_t ws_size,
                              hipStream_t stream) {
    (void)in_sizes; (void)n_in; (void)out_size; (void)ws_size;
    const float* x    = (const float*)d_in[0];
    const float* ctrl = (const float*)d_in[1];
    const float* f1   = (const float*)d_in[2];
    const float* bias = (const float*)d_in[3];
    const float* f2   = (const float*)d_in[4];
    float* out = (float*)d_out;

    char* ws = (char*)d_ws;
    int*    idx  = (int*)ws;                        // 128 KB
    ushort* Hb   = (ushort*)(ws + 131072);          // 2 MB
    ushort* f1F  = (ushort*)(ws + 2228224);         // 8 MB
    ushort* f2T  = (ushort*)(ws + 10616832);        // 8 MB
    ushort* xb   = (ushort*)(ws + 19005440);        // 16 MB
    uchar*  idx8 = (uchar*)(ws + 35782656);         // 32 KB (end ~34.2 MB)

    k_fused1<<<1280, 256, 0, stream>>>(x, ctrl, f1, f2, idx, idx8, xb, f1F, f2T);

    k_h_mfma<<<NSLOT * 4, 256, 0, stream>>>(xb, f1F, bias, idx, Hb);

    const size_t lds3 = 163840;                     // 160 KiB exactly
    hipFuncSetAttribute((const void*)k_out_mfma,
                        hipFuncAttributeMaxDynamicSharedMemorySize, (int)lds3);
    k_out_mfma<<<256, 256, lds3, stream>>>(Hb, f2T, idx8, out);
}